// Round 1
// baseline (431.402 us; speedup 1.0000x reference)
//
#include <hip/hip_runtime.h>

typedef __attribute__((ext_vector_type(8))) __bf16 bf16x8;
typedef __attribute__((ext_vector_type(4))) float f32x4;

__device__ __forceinline__ unsigned short f2bf(float x) {
  union { float f; unsigned int u; } v; v.f = x;
  unsigned int r = v.u + 0x7fffu + ((v.u >> 16) & 1u);
  return (unsigned short)(r >> 16);
}
__device__ __forceinline__ float bf2f(unsigned short x) {
  union { unsigned int u; float f; } v; v.u = ((unsigned int)x) << 16;
  return v.f;
}
__device__ __forceinline__ void g2l16(const void* g, void* l) {
  __builtin_amdgcn_global_load_lds((const __attribute__((address_space(1))) void*)g,
                                   (__attribute__((address_space(3))) void*)l, 16, 0, 0);
}

#define BARX()                                  \
  do {                                          \
    asm volatile("" ::: "memory");              \
    __builtin_amdgcn_s_barrier();               \
    asm volatile("" ::: "memory");              \
  } while (0)

// ---------------- fused input prep ----------------
// blocks [0,8192):        x fp32 -> bf16            (4 elems/thread)
// blocks [8192,11264):    wqkv [2048,6144] -> transposed bf16 [6144,2048]
// blocks [11264,12288):   wout [2048,2048] -> transposed bf16 [2048,2048]
__global__ __launch_bounds__(256) void prep_k(const float* __restrict__ x,
                                              const float* __restrict__ wq,
                                              const float* __restrict__ wo,
                                              unsigned short* __restrict__ xb,
                                              unsigned short* __restrict__ wqT,
                                              unsigned short* __restrict__ woT) {
  __shared__ unsigned short t[64][65];
  const int b = blockIdx.x;
  if (b < 8192) {
    int i = b * 256 + threadIdx.x;
    float4 v = ((const float4*)x)[i];
    ushort4 o;
    o.x = f2bf(v.x); o.y = f2bf(v.y); o.z = f2bf(v.z); o.w = f2bf(v.w);
    ((ushort4*)xb)[i] = o;
    return;
  }
  const float* in; unsigned short* out; int C, c0, r0;
  const int R = 2048;
  if (b < 11264) { int bb = b - 8192;  in = wq; out = wqT; C = 6144; c0 = (bb % 96) * 64; r0 = (bb / 96) * 64; }
  else           { int bb = b - 11264; in = wo; out = woT; C = 2048; c0 = (bb & 31) * 64; r0 = (bb >> 5) * 64; }
  const int tx = threadIdx.x & 63, tg = threadIdx.x >> 6;
#pragma unroll
  for (int i = 0; i < 16; i++) {
    int r = i * 4 + tg;
    t[r][tx] = f2bf(in[(size_t)(r0 + r) * C + c0 + tx]);
  }
  __syncthreads();
#pragma unroll
  for (int i = 0; i < 16; i++) {
    int c = i * 4 + tg;
    out[(size_t)(c0 + c) * R + r0 + tx] = t[tx][c];
  }
}

// ---------------- QKV GEMM: 256x256 8-phase (m201 template, plain HIP) ----------------
// C[4096,6144] = xb[4096,2048] @ wqkvT[6144,2048]^T, bf16 in, fused epilogue:
//   q/k: RoPE (per 128x128 head-subtile via LDS bf16 tile stride 130)
//   v:   transposed store into vt [B,H,D,S] via LDS tile stride 136
// Geometry: BM=BN=256, BK=64, 512 thr (8 waves 2Mx4N), per-wave 128x64 (acc[8][4]).
// LDS 128 KiB: A = 2dbuf x 2half x (128x64 bf16, XOR-swizzled 16B chunks); B same at +64KiB.
// Schedule per K-tile t (4 phases): stage stream order {B0,B1,A0,A1}, issue lead 7 halves,
//   P0: read A rows0-3 + all B, stage(4t+7)=A1(t+1);  P1: stage(4t+8)=B0(t+2);
//   P2: read A rows4-7, stage(4t+9)=B1(t+2);          P3: stage(4t+10)=A0(t+2),
//   then vmcnt(6) (vmcnt(0) only before last tile). 2 raw s_barriers per phase, setprio(1)
//   around each 16-MFMA cluster. Slot overwrite issues always fall after the phase-end
//   barrier following that slot's last reads (A reads: P0/P2; B reads: P0).
__global__ __launch_bounds__(512, 2) void gemm8_qkv(const unsigned short* __restrict__ A,
                                                    const unsigned short* __restrict__ BT,
                                                    unsigned short* __restrict__ oq,
                                                    unsigned short* __restrict__ ok,
                                                    unsigned short* __restrict__ ov) {
  __shared__ __align__(16) unsigned short smem8[65536];   // 131072 B
  const int tid = threadIdx.x;
  const int w = tid >> 6, lane = tid & 63;
  const int quad = lane >> 4, l16 = lane & 15;
  // bijective XCD swizzle (384 blocks, 384 % 8 == 0)
  const int id = (int)blockIdx.x;
  const int wg = (id & 7) * 48 + (id >> 3);
  const int bx = wg % 24, by = wg / 24;
  const int m0 = by * 256, n0 = bx * 256;
  const int wm = (w >> 2) * 128, wn = (w & 3) * 64;
  f32x4 acc[8][4] = {};

  // staging: per half-tile (128 rows x 64 k) each thread does 2 x g2l16(16B)
  const int rr = tid >> 3, csw = (tid & 7) ^ (rr & 7);
  const unsigned short* gA = A + (size_t)(m0 + rr) * 2048 + csw * 8;
  const unsigned short* gB = BT + (size_t)(n0 + rr) * 2048 + csw * 8;
  char* ldst = (char*)smem8 + tid * 16;
  auto STAGE = [&](int s) {
    if (s <= 127) {
      const int tau = s >> 2, u = s & 3, hh = u & 1;
      char* l = ldst + ((u < 2) ? 65536 : 0) + (tau & 1) * 32768 + hh * 16384;
      const unsigned short* g = ((u < 2) ? gB : gA) + (size_t)hh * 128 * 2048 + tau * 64;
      g2l16(g, (void*)l);
      g2l16(g + (size_t)64 * 2048, (void*)(l + 8192));
    }
  };

  // LDS read bases (XOR swizzle matches staging: phys chunk = logical ^ (row&7))
  const char* sA = (const char*)smem8 + (wm >> 7) * 16384 + l16 * 128;
  const char* sB = (const char*)smem8 + 65536 + (wn >> 7) * 16384 + ((wn & 64) + l16) * 128;
  const int x0 = (quad ^ (l16 & 7)) * 16;
  const int x1 = ((4 + quad) ^ (l16 & 7)) * 16;

#define KTILE(T, PB, NV)                                                                          \
  {                                                                                               \
    const int _t = (T);                                                                           \
    bf16x8 a0[4][2], bq[4][2];                                                                    \
    _Pragma("unroll") for (int i = 0; i < 4; ++i) {                                               \
      a0[i][0] = *(const bf16x8*)(sA + (PB) + i * 2048 + x0);                                     \
      a0[i][1] = *(const bf16x8*)(sA + (PB) + i * 2048 + x1);                                     \
    }                                                                                             \
    _Pragma("unroll") for (int j = 0; j < 4; ++j) {                                               \
      bq[j][0] = *(const bf16x8*)(sB + (PB) + j * 2048 + x0);                                     \
      bq[j][1] = *(const bf16x8*)(sB + (PB) + j * 2048 + x1);                                     \
    }                                                                                             \
    STAGE(4 * _t + 7);                                                                            \
    BARX();                                                                                       \
    __builtin_amdgcn_s_setprio(1);                                                                \
    _Pragma("unroll") for (int ks = 0; ks < 2; ++ks)                                              \
      _Pragma("unroll") for (int i = 0; i < 4; ++i)                                               \
        _Pragma("unroll") for (int j = 0; j < 2; ++j)                                             \
          acc[i][j] = __builtin_amdgcn_mfma_f32_16x16x32_bf16(a0[i][ks], bq[j][ks], acc[i][j], 0, 0, 0); \
    __builtin_amdgcn_s_setprio(0);                                                                \
    BARX();                                                                                       \
    STAGE(4 * _t + 8);                                                                            \
    BARX();                                                                                       \
    __builtin_amdgcn_s_setprio(1);                                                                \
    _Pragma("unroll") for (int ks = 0; ks < 2; ++ks)                                              \
      _Pragma("unroll") for (int i = 0; i < 4; ++i)                                               \
        _Pragma("unroll") for (int j = 2; j < 4; ++j)                                             \
          acc[i][j] = __builtin_amdgcn_mfma_f32_16x16x32_bf16(a0[i][ks], bq[j][ks], acc[i][j], 0, 0, 0); \
    __builtin_amdgcn_s_setprio(0);                                                                \
    BARX();                                                                                       \
    bf16x8 a1[4][2];                                                                              \
    _Pragma("unroll") for (int i = 0; i < 4; ++i) {                                               \
      a1[i][0] = *(const bf16x8*)(sA + (PB) + (i + 4) * 2048 + x0);                               \
      a1[i][1] = *(const bf16x8*)(sA + (PB) + (i + 4) * 2048 + x1);                               \
    }                                                                                             \
    STAGE(4 * _t + 9);                                                                            \
    BARX();                                                                                       \
    __builtin_amdgcn_s_setprio(1);                                                                \
    _Pragma("unroll") for (int ks = 0; ks < 2; ++ks)                                              \
      _Pragma("unroll") for (int i = 0; i < 4; ++i)                                               \
        _Pragma("unroll") for (int j = 0; j < 2; ++j)                                             \
          acc[i + 4][j] = __builtin_amdgcn_mfma_f32_16x16x32_bf16(a1[i][ks], bq[j][ks], acc[i + 4][j], 0, 0, 0); \
    __builtin_amdgcn_s_setprio(0);                                                                \
    BARX();                                                                                       \
    STAGE(4 * _t + 10);                                                                           \
    BARX();                                                                                       \
    __builtin_amdgcn_s_setprio(1);                                                                \
    _Pragma("unroll") for (int ks = 0; ks < 2; ++ks)                                              \
      _Pragma("unroll") for (int i = 0; i < 4; ++i)                                               \
        _Pragma("unroll") for (int j = 2; j < 4; ++j)                                             \
          acc[i + 4][j] = __builtin_amdgcn_mfma_f32_16x16x32_bf16(a1[i][ks], bq[j][ks], acc[i + 4][j], 0, 0, 0); \
    __builtin_amdgcn_s_setprio(0);                                                                \
    if ((NV) == 6) asm volatile("s_waitcnt vmcnt(6)" ::: "memory");                               \
    else if ((NV) == 0) asm volatile("s_waitcnt vmcnt(0)" ::: "memory");                          \
    BARX();                                                                                       \
  }

  // prologue: issue half-tiles 0..6 (tile0 {B0,B1,A0,A1} + tile1 {B0,B1,A0})
  for (int s = 0; s < 7; ++s) STAGE(s);
  asm volatile("s_waitcnt vmcnt(6)" ::: "memory");
  BARX();

  for (int t2 = 0; t2 < 32; t2 += 2) {
    KTILE(t2, 0, (t2 == 30) ? 0 : 6);
    KTILE(t2 + 1, 32768, (t2 + 1 == 31) ? -1 : 6);
  }
#undef KTILE

  // ---------------- fused epilogue (two passes: head-col halves ch=0,1) ----------------
  const int which = n0 >> 11;          // 0=q 1=k 2=v
  const int h2 = (n0 >> 7) & 15;       // head of ch=0
  const int bi2 = m0 >> 11, s0 = m0 & 2047;
  if (which < 2) {
    unsigned short* dst = which ? ok : oq;
    const float scale = which ? 1.0f : 0.08838834764831845f;
    const int d = tid & 63, tg = (tid >> 6) & 3, rh = tid >> 8;
    const float fr = exp2f(-(float)d * (13.287712379549449f / 64.0f));
    for (int ch = 0; ch < 2; ++ch) {
      BARX();
      if (((w >> 1) & 1) == ch) {
        const int rw = w >> 2, cl = (w & 1) * 64;
#pragma unroll
        for (int i = 0; i < 8; ++i)
#pragma unroll
          for (int r = 0; r < 4; ++r) {
            int row = i * 16 + quad * 4 + r;
#pragma unroll
            for (int j = 0; j < 4; ++j)
              smem8[rw * 16640 + row * 130 + cl + j * 16 + l16] = f2bf(acc[i][j][r]);
          }
      }
      BARX();
      const int h = (h2 + ch) & 15;
      const size_t hb = ((size_t)(bi2 * 16 + h) * 2048 + s0 + rh * 128) * 128;
      const unsigned short* tl = smem8 + rh * 16640;
#pragma unroll
      for (int i = 0; i < 32; ++i) {
        int r = i * 4 + tg;
        float xa = bf2f(tl[r * 130 + d]);
        float xb2 = bf2f(tl[r * 130 + 64 + d]);
        float sn, cs;
        __sincosf((float)(s0 + rh * 128 + r) * fr, &sn, &cs);
        dst[hb + (size_t)r * 128 + d]      = f2bf((xa * cs - xb2 * sn) * scale);
        dst[hb + (size_t)r * 128 + 64 + d] = f2bf((xb2 * cs + xa * sn) * scale);
      }
    }
  } else {
    const int sc = tid & 15, dbase = (tid >> 4) & 15, rh = tid >> 8;
    for (int ch = 0; ch < 2; ++ch) {
      BARX();
      if (((w >> 1) & 1) == ch) {
        const int rw = w >> 2, cl = (w & 1) * 64;
#pragma unroll
        for (int i = 0; i < 8; ++i)
#pragma unroll
          for (int j = 0; j < 4; ++j) {
            int row = i * 16 + quad * 4;
            int col = cl + j * 16 + l16;
            ushort4 t4;
            t4.x = f2bf(acc[i][j][0]); t4.y = f2bf(acc[i][j][1]);
            t4.z = f2bf(acc[i][j][2]); t4.w = f2bf(acc[i][j][3]);
            *(ushort4*)&smem8[rw * 17408 + col * 136 + row] = t4;
          }
      }
      BARX();
      const int h = (h2 + ch) & 15;
      const size_t vrb = ((size_t)(bi2 * 16 + h) * 128) * 2048 + s0 + rh * 128;
#pragma unroll
      for (int vv = 0; vv < 8; ++vv) {
        int dd = dbase + vv * 16;
        uint4 val = *(const uint4*)&smem8[rh * 17408 + dd * 136 + sc * 8];
        *(uint4*)(ov + vrb + (size_t)dd * 2048 + sc * 8) = val;
      }
    }
  }
}

// ---------------- GEMM: C[M,N] = A[M,K](bf16) @ BT[N,K](bf16)^T ----------------
// 128x128 tile, BK=64, XOR-swizzled conflict-free LDS (R4 structure).
// Used only with EPI=1 now (out projection; 512-block grid — 256^2 template would
// leave half the CUs idle at N=2048).
template <int EPI>
__global__ __launch_bounds__(256) void gemm_bt_k(const unsigned short* __restrict__ A,
                                                 const unsigned short* __restrict__ BT,
                                                 int K, int N,
                                                 float* __restrict__ outF,
                                                 unsigned short* __restrict__ oq,
                                                 unsigned short* __restrict__ ok,
                                                 unsigned short* __restrict__ ov) {
  __shared__ __align__(16) unsigned short smem[17408];
  unsigned short* lA = smem;
  unsigned short* lB = smem + 8192;
  const int tid = threadIdx.x;
  const int w = tid >> 6, lane = tid & 63;
  const int quad = lane >> 4, l16 = lane & 15;
  const int m0 = blockIdx.y * 128, n0 = blockIdx.x * 128;
  const int wm = (w >> 1) * 64, wn = (w & 1) * 64;
  f32x4 acc[4][4] = {};
  const int srow = tid >> 3;
  const int schunk = (tid & 7) ^ (srow & 7);
  const unsigned short* gA = A + (size_t)(m0 + srow) * K + schunk * 8;
  const unsigned short* gB = BT + (size_t)(n0 + srow) * K + schunk * 8;
  char* ldA = (char*)lA + tid * 16;
  char* ldB = (char*)lB + tid * 16;
  const size_t rskip = (size_t)32 * K;
  for (int k0 = 0; k0 < K; k0 += 64) {
#pragma unroll
    for (int j = 0; j < 4; j++) {
      g2l16(gA + k0 + j * rskip, ldA + j * 4096);
      g2l16(gB + k0 + j * rskip, ldB + j * 4096);
    }
    __syncthreads();
#pragma unroll
    for (int ks = 0; ks < 2; ks++) {
      bf16x8 af[4], bfv[4];
#pragma unroll
      for (int i = 0; i < 4; i++)
        af[i] = *(const bf16x8*)((const char*)lA + (size_t)(wm + i * 16 + l16) * 128 +
                                 ((size_t)((ks * 4 + quad) ^ (l16 & 7)) * 16));
#pragma unroll
      for (int j = 0; j < 4; j++)
        bfv[j] = *(const bf16x8*)((const char*)lB + (size_t)(wn + j * 16 + l16) * 128 +
                                  ((size_t)((ks * 4 + quad) ^ (l16 & 7)) * 16));
#pragma unroll
      for (int i = 0; i < 4; i++)
#pragma unroll
        for (int j = 0; j < 4; j++)
          acc[i][j] = __builtin_amdgcn_mfma_f32_16x16x32_bf16(af[i], bfv[j], acc[i][j], 0, 0, 0);
    }
    __syncthreads();
  }
  if (EPI == 0) {
    // (unused in this version — QKV handled by gemm8_qkv)
  } else {
#pragma unroll
    for (int i = 0; i < 4; i++)
#pragma unroll
      for (int r = 0; r < 4; r++) {
        size_t rowb = (size_t)(m0 + wm + i * 16 + quad * 4 + r) * N;
#pragma unroll
        for (int j = 0; j < 4; j++)
          outF[rowb + n0 + wn + j * 16 + l16] = acc[i][j][r];
      }
  }
}

// ---------------- flash attention (R4 structure, g2l16-staged) ----------------
__global__ __launch_bounds__(256, 2) void attn_k(const unsigned short* __restrict__ qb,
                                                 const unsigned short* __restrict__ kb,
                                                 const unsigned short* __restrict__ vt,
                                                 unsigned short* __restrict__ ob) {
  __shared__ __align__(16) unsigned short lK[64 * 128];
  __shared__ __align__(16) unsigned short lV[128 * 64];
  __shared__ __align__(16) __bf16 pbuf[4][32 * 72];
  const int tid = threadIdx.x;
  const int w = tid >> 6, lane = tid & 63;
  const int quad = lane >> 4, l16 = lane & 15;
  const int qt = (blockIdx.y < 16) ? (int)blockIdx.x : 15 - (int)blockIdx.x;
  const int bh = blockIdx.y;
  const int bi = bh >> 4, h = bh & 15;
  const int q0w = qt * 128 + w * 32;
  const unsigned short* qp = qb + (size_t)bh * 2048 * 128;
  const unsigned short* kp = kb + (size_t)bh * 2048 * 128;
  const unsigned short* vp = vt + (size_t)bh * 128 * 2048;
  __bf16* pw = pbuf[w];

  bf16x8 qf[2][4];
#pragma unroll
  for (int rg = 0; rg < 2; rg++) {
    const unsigned short* qr = qp + (size_t)(q0w + rg * 16 + l16) * 128 + quad * 8;
#pragma unroll
    for (int st = 0; st < 4; st++) qf[rg][st] = *(const bf16x8*)(qr + st * 32);
  }
  f32x4 o[2][8] = {};
  f32x4 lsum[2] = {};

  const int krow = tid >> 4;
  const int kcg = (tid & 15) ^ krow;
  const int vd = tid >> 3;
  const int vsg = (tid & 7) ^ ((tid >> 3) & 7);
  unsigned short* lKdst = lK + (size_t)tid * 8;
  unsigned short* lVdst = lV + (size_t)tid * 8;

  const int nkt = 2 * qt + 2;
  const int myNkt = (q0w + 31) / 64 + 1;
  for (int kt = 0; kt < nkt; kt++) {
    const int kt0 = kt * 64;
#pragma unroll
    for (int j = 0; j < 4; j++) {
      g2l16(kp + (size_t)(kt0 + j * 16 + krow) * 128 + kcg * 8, lKdst + j * 2048);
      g2l16(vp + (size_t)(j * 32 + vd) * 2048 + kt0 + vsg * 8, lVdst + j * 2048);
    }
    __syncthreads();
    if (kt < myNkt) {
      f32x4 sc[2][4] = {};
#pragma unroll
      for (int ct = 0; ct < 4; ct++) {
        const int nrow = ct * 16 + l16;
#pragma unroll
        for (int st = 0; st < 4; st++) {
          bf16x8 kf = *(const bf16x8*)(lK + ((size_t)nrow * 16 + ((st * 4 + quad) ^ l16)) * 8);
          sc[0][ct] = __builtin_amdgcn_mfma_f32_16x16x32_bf16(qf[0][st], kf, sc[0][ct], 0, 0, 0);
          sc[1][ct] = __builtin_amdgcn_mfma_f32_16x16x32_bf16(qf[1][st], kf, sc[1][ct], 0, 0, 0);
        }
      }
      const bool needmask = (kt == myNkt - 1);
#pragma unroll
      for (int rg = 0; rg < 2; rg++)
#pragma unroll
        for (int ct = 0; ct < 4; ct++) {
          const int col = kt0 + ct * 16 + l16;
          const int rowb = q0w + rg * 16 + quad * 4;
#pragma unroll
          for (int r = 0; r < 4; r++) {
            float s = sc[rg][ct][r];
            if (needmask && col > rowb + r) s = -1e30f;
            float e = __expf(s);
            lsum[rg][r] += e;
            pw[(rg * 16 + quad * 4 + r) * 72 + ct * 16 + l16] = (__bf16)e;
          }
        }
      bf16x8 pf[2][2];
#pragma unroll
      for (int rg = 0; rg < 2; rg++)
#pragma unroll
        for (int sb = 0; sb < 2; sb++)
          pf[rg][sb] = *(const bf16x8*)(pw + (rg * 16 + l16) * 72 + sb * 32 + quad * 8);
#pragma unroll
      for (int dt = 0; dt < 8; dt++) {
#pragma unroll
        for (int sb = 0; sb < 2; sb++) {
          bf16x8 vf = *(const bf16x8*)(lV +
              ((size_t)(dt * 16 + l16) * 8 + ((sb * 4 + quad) ^ (l16 & 7))) * 8);
          o[0][dt] = __builtin_amdgcn_mfma_f32_16x16x32_bf16(pf[0][sb], vf, o[0][dt], 0, 0, 0);
          o[1][dt] = __builtin_amdgcn_mfma_f32_16x16x32_bf16(pf[1][sb], vf, o[1][dt], 0, 0, 0);
        }
      }
    }
    __syncthreads();
  }
#pragma unroll
  for (int m = 1; m < 16; m <<= 1)
#pragma unroll
    for (int rg = 0; rg < 2; rg++)
#pragma unroll
      for (int r = 0; r < 4; r++)
        lsum[rg][r] += __shfl_xor(lsum[rg][r], m, 64);
  float inv[2][4];
#pragma unroll
  for (int rg = 0; rg < 2; rg++)
#pragma unroll
    for (int r = 0; r < 4; r++) inv[rg][r] = 1.0f / lsum[rg][r];
#pragma unroll
  for (int rg = 0; rg < 2; rg++)
#pragma unroll
    for (int dt = 0; dt < 8; dt++)
#pragma unroll
      for (int r = 0; r < 4; r++)
        ob[(size_t)(bi * 2048 + q0w + rg * 16 + quad * 4 + r) * 2048 + h * 128 + dt * 16 + l16] =
            f2bf(o[rg][dt][r] * inv[rg][r]);
}

extern "C" void kernel_launch(void* const* d_in, const int* in_sizes, int n_in,
                              void* d_out, int out_size, void* d_ws, size_t ws_size,
                              hipStream_t stream) {
  const float* x = (const float*)d_in[0];
  const float* wqkv = (const float*)d_in[1];
  const float* wout = (const float*)d_in[2];
  // d_in[3] = mask, unused (causal analytically)
  char* ws = (char*)d_ws;
  const size_t MiB = 1ull << 20;
  unsigned short* xb    = (unsigned short*)(ws + 0);         // [4096,2048] bf16   16 MiB
  unsigned short* wqkvT = (unsigned short*)(ws + 16 * MiB);  // [6144,2048] bf16   24 MiB
  unsigned short* woutT = (unsigned short*)(ws + 40 * MiB);  // [2048,2048] bf16    8 MiB
  unsigned short* qb    = (unsigned short*)(ws + 48 * MiB);  // [32,2048,128] bf16 16 MiB
  unsigned short* kb    = (unsigned short*)(ws + 64 * MiB);  // [32,2048,128]      16 MiB
  unsigned short* vtb   = (unsigned short*)(ws + 80 * MiB);  // [32,128,2048]      16 MiB
  unsigned short* attnb = (unsigned short*)(ws + 96 * MiB);  // [4096,2048] bf16   16 MiB
  float* outF = (float*)d_out;

  prep_k<<<12288, 256, 0, stream>>>(x, wqkv, wout, xb, wqkvT, woutT);
  gemm8_qkv<<<384, 512, 0, stream>>>(xb, wqkvT, qb, kb, vtb);
  attn_k<<<dim3(16, 32), 256, 0, stream>>>(qb, kb, vtb, attnb);
  gemm_bt_k<1><<<dim3(16, 32), 256, 0, stream>>>(attnb, woutT, 2048, 2048, outF,
                                                 nullptr, nullptr, nullptr);
}

// Round 2
// 428.670 us; speedup vs baseline: 1.0064x; 1.0064x over previous
//
#include <hip/hip_runtime.h>

typedef __attribute__((ext_vector_type(8))) __bf16 bf16x8;
typedef __attribute__((ext_vector_type(4))) float f32x4;

__device__ __forceinline__ unsigned short f2bf(float x) {
  union { float f; unsigned int u; } v; v.f = x;
  unsigned int r = v.u + 0x7fffu + ((v.u >> 16) & 1u);
  return (unsigned short)(r >> 16);
}
__device__ __forceinline__ float bf2f(unsigned short x) {
  union { unsigned int u; float f; } v; v.u = ((unsigned int)x) << 16;
  return v.f;
}
__device__ __forceinline__ void g2l16(const void* g, void* l) {
  __builtin_amdgcn_global_load_lds((const __attribute__((address_space(1))) void*)g,
                                   (__attribute__((address_space(3))) void*)l, 16, 0, 0);
}

#define BARX()                                  \
  do {                                          \
    asm volatile("" ::: "memory");              \
    __builtin_amdgcn_s_barrier();               \
    asm volatile("" ::: "memory");              \
  } while (0)

// ---------------- fused input prep ----------------
__global__ __launch_bounds__(256) void prep_k(const float* __restrict__ x,
                                              const float* __restrict__ wq,
                                              const float* __restrict__ wo,
                                              unsigned short* __restrict__ xb,
                                              unsigned short* __restrict__ wqT,
                                              unsigned short* __restrict__ woT) {
  __shared__ unsigned short t[64][65];
  const int b = blockIdx.x;
  if (b < 8192) {
    int i = b * 256 + threadIdx.x;
    float4 v = ((const float4*)x)[i];
    ushort4 o;
    o.x = f2bf(v.x); o.y = f2bf(v.y); o.z = f2bf(v.z); o.w = f2bf(v.w);
    ((ushort4*)xb)[i] = o;
    return;
  }
  const float* in; unsigned short* out; int C, c0, r0;
  const int R = 2048;
  if (b < 11264) { int bb = b - 8192;  in = wq; out = wqT; C = 6144; c0 = (bb % 96) * 64; r0 = (bb / 96) * 64; }
  else           { int bb = b - 11264; in = wo; out = woT; C = 2048; c0 = (bb & 31) * 64; r0 = (bb >> 5) * 64; }
  const int tx = threadIdx.x & 63, tg = threadIdx.x >> 6;
#pragma unroll
  for (int i = 0; i < 16; i++) {
    int r = i * 4 + tg;
    t[r][tx] = f2bf(in[(size_t)(r0 + r) * C + c0 + tx]);
  }
  __syncthreads();
#pragma unroll
  for (int i = 0; i < 16; i++) {
    int c = i * 4 + tg;
    out[(size_t)(c0 + c) * R + r0 + tx] = t[tx][c];
  }
}

// ---------------- QKV GEMM: 256x256 8-phase (m201 template, plain HIP) ----------------
// R2 fix: per-phase fragment reads (peak live frags 96->64 VGPR) to kill the
// register spill that was polluting vmcnt accounting (R1: WRITE_SIZE 92MB vs
// 49MB of real output => scratch traffic; vmcnt(6) then drained the pipeline
// every tile -> MfmaUtil 24%). Phases per K-tile:
//   P0: read a0(8)+b0(4), STAGE(4t+7)=A1(t+1), bar, 16 MFMA rows0-3 x cols0-1
//   P1: read b1(4),       STAGE(4t+8)=B0(t+2), bar, 16 MFMA rows0-3 x cols2-3
//   P2: read a1(8),       STAGE(4t+9)=B1(t+2), bar, 16 MFMA rows4-7 x cols0-1
//   P3: (no reads)        STAGE(4t+10)=A0(t+2),bar, 16 MFMA rows4-7 x cols2-3, vmcnt(6)
// Slot-overwrite stages always issue after the end-barrier of the phase with that
// slot's last LDS reads. vmcnt(6) == 3 half-tiles (2 loads each) in flight.
__global__ __launch_bounds__(512) void gemm8_qkv(const unsigned short* __restrict__ A,
                                                 const unsigned short* __restrict__ BT,
                                                 unsigned short* __restrict__ oq,
                                                 unsigned short* __restrict__ ok,
                                                 unsigned short* __restrict__ ov) {
  __shared__ __align__(16) unsigned short smem8[65536];   // 131072 B
  const int tid = threadIdx.x;
  const int w = tid >> 6, lane = tid & 63;
  const int quad = lane >> 4, l16 = lane & 15;
  // bijective XCD swizzle (384 blocks, 384 % 8 == 0)
  const int id = (int)blockIdx.x;
  const int wg = (id & 7) * 48 + (id >> 3);
  const int bx = wg % 24, by = wg / 24;
  const int m0 = by * 256, n0 = bx * 256;
  const int wm = (w >> 2) * 128, wn = (w & 3) * 64;
  f32x4 acc[8][4] = {};

  // staging: per half-tile (128 rows x 64 k) each thread does 2 x g2l16(16B)
  const int rr = tid >> 3, csw = (tid & 7) ^ (rr & 7);
  const unsigned short* gA = A + (size_t)(m0 + rr) * 2048 + csw * 8;
  const unsigned short* gB = BT + (size_t)(n0 + rr) * 2048 + csw * 8;
  char* ldst = (char*)smem8 + tid * 16;
  auto STAGE = [&](int s) {
    if (s <= 127) {
      const int tau = s >> 2, u = s & 3, hh = u & 1;
      char* l = ldst + ((u < 2) ? 65536 : 0) + (tau & 1) * 32768 + hh * 16384;
      const unsigned short* g = ((u < 2) ? gB : gA) + (size_t)hh * 128 * 2048 + tau * 64;
      g2l16(g, (void*)l);
      g2l16(g + (size_t)64 * 2048, (void*)(l + 8192));
    }
  };

  // LDS read bases (XOR swizzle matches staging: phys chunk = logical ^ (row&7))
  const char* sA = (const char*)smem8 + (wm >> 7) * 16384 + l16 * 128;
  const char* sB = (const char*)smem8 + 65536 + (wn >> 7) * 16384 + ((wn & 64) + l16) * 128;
  const int x0 = (quad ^ (l16 & 7)) * 16;
  const int x1 = ((4 + quad) ^ (l16 & 7)) * 16;

#define KTILE(T, PB, NV)                                                                          \
  {                                                                                               \
    bf16x8 a0[4][2], a1[4][2], b0[2][2], b1[2][2];                                                \
    _Pragma("unroll") for (int i = 0; i < 4; ++i) {                                               \
      a0[i][0] = *(const bf16x8*)(sA + (PB) + i * 2048 + x0);                                     \
      a0[i][1] = *(const bf16x8*)(sA + (PB) + i * 2048 + x1);                                     \
    }                                                                                             \
    _Pragma("unroll") for (int j = 0; j < 2; ++j) {                                               \
      b0[j][0] = *(const bf16x8*)(sB + (PB) + j * 2048 + x0);                                     \
      b0[j][1] = *(const bf16x8*)(sB + (PB) + j * 2048 + x1);                                     \
    }                                                                                             \
    STAGE(4 * (T) + 7);                                                                           \
    BARX();                                                                                       \
    asm volatile("s_waitcnt lgkmcnt(0)" ::: "memory");                                            \
    __builtin_amdgcn_s_setprio(1);                                                                \
    _Pragma("unroll") for (int ks = 0; ks < 2; ++ks)                                              \
      _Pragma("unroll") for (int i = 0; i < 4; ++i)                                               \
        _Pragma("unroll") for (int j = 0; j < 2; ++j)                                             \
          acc[i][j] = __builtin_amdgcn_mfma_f32_16x16x32_bf16(a0[i][ks], b0[j][ks], acc[i][j], 0, 0, 0); \
    __builtin_amdgcn_s_setprio(0);                                                                \
    BARX();                                                                                       \
    _Pragma("unroll") for (int j = 0; j < 2; ++j) {                                               \
      b1[j][0] = *(const bf16x8*)(sB + (PB) + (j + 2) * 2048 + x0);                               \
      b1[j][1] = *(const bf16x8*)(sB + (PB) + (j + 2) * 2048 + x1);                               \
    }                                                                                             \
    STAGE(4 * (T) + 8);                                                                           \
    BARX();                                                                                       \
    asm volatile("s_waitcnt lgkmcnt(0)" ::: "memory");                                            \
    __builtin_amdgcn_s_setprio(1);                                                                \
    _Pragma("unroll") for (int ks = 0; ks < 2; ++ks)                                              \
      _Pragma("unroll") for (int i = 0; i < 4; ++i)                                               \
        _Pragma("unroll") for (int j = 0; j < 2; ++j)                                             \
          acc[i][j + 2] = __builtin_amdgcn_mfma_f32_16x16x32_bf16(a0[i][ks], b1[j][ks], acc[i][j + 2], 0, 0, 0); \
    __builtin_amdgcn_s_setprio(0);                                                                \
    BARX();                                                                                       \
    _Pragma("unroll") for (int i = 0; i < 4; ++i) {                                               \
      a1[i][0] = *(const bf16x8*)(sA + (PB) + (i + 4) * 2048 + x0);                               \
      a1[i][1] = *(const bf16x8*)(sA + (PB) + (i + 4) * 2048 + x1);                               \
    }                                                                                             \
    STAGE(4 * (T) + 9);                                                                           \
    BARX();                                                                                       \
    asm volatile("s_waitcnt lgkmcnt(0)" ::: "memory");                                            \
    __builtin_amdgcn_s_setprio(1);                                                                \
    _Pragma("unroll") for (int ks = 0; ks < 2; ++ks)                                              \
      _Pragma("unroll") for (int i = 0; i < 4; ++i)                                               \
        _Pragma("unroll") for (int j = 0; j < 2; ++j)                                             \
          acc[i + 4][j] = __builtin_amdgcn_mfma_f32_16x16x32_bf16(a1[i][ks], b0[j][ks], acc[i + 4][j], 0, 0, 0); \
    __builtin_amdgcn_s_setprio(0);                                                                \
    BARX();                                                                                       \
    STAGE(4 * (T) + 10);                                                                          \
    BARX();                                                                                       \
    __builtin_amdgcn_s_setprio(1);                                                                \
    _Pragma("unroll") for (int ks = 0; ks < 2; ++ks)                                              \
      _Pragma("unroll") for (int i = 0; i < 4; ++i)                                               \
        _Pragma("unroll") for (int j = 0; j < 2; ++j)                                             \
          acc[i + 4][j + 2] = __builtin_amdgcn_mfma_f32_16x16x32_bf16(a1[i][ks], b1[j][ks], acc[i + 4][j + 2], 0, 0, 0); \
    __builtin_amdgcn_s_setprio(0);                                                                \
    if ((NV) == 6) asm volatile("s_waitcnt vmcnt(6)" ::: "memory");                               \
    else if ((NV) == 0) asm volatile("s_waitcnt vmcnt(0)" ::: "memory");                          \
    BARX();                                                                                       \
  }

  // prologue: issue half-tiles 0..6 (tile0 {B0,B1,A0,A1} + tile1 {B0,B1,A0})
  for (int s = 0; s < 7; ++s) STAGE(s);
  asm volatile("s_waitcnt vmcnt(6)" ::: "memory");
  BARX();

  for (int t2 = 0; t2 < 32; t2 += 2) {
    KTILE(t2, 0, (t2 == 30) ? 0 : 6);
    KTILE(t2 + 1, 32768, (t2 + 1 == 31) ? -1 : 6);
  }
#undef KTILE

  // ---------------- fused epilogue (two passes: head-col halves ch=0,1) ----------------
  const int which = n0 >> 11;          // 0=q 1=k 2=v
  const int h2 = (n0 >> 7) & 15;       // head of ch=0
  const int bi2 = m0 >> 11, s0 = m0 & 2047;
  if (which < 2) {
    unsigned short* dst = which ? ok : oq;
    const float scale = which ? 1.0f : 0.08838834764831845f;
    const int d = tid & 63, tg = (tid >> 6) & 3, rh = tid >> 8;
    const float fr = exp2f(-(float)d * (13.287712379549449f / 64.0f));
    for (int ch = 0; ch < 2; ++ch) {
      BARX();
      if (((w >> 1) & 1) == ch) {
        const int rw = w >> 2, cl = (w & 1) * 64;
#pragma unroll
        for (int i = 0; i < 8; ++i)
#pragma unroll
          for (int r = 0; r < 4; ++r) {
            int row = i * 16 + quad * 4 + r;
#pragma unroll
            for (int j = 0; j < 4; ++j)
              smem8[rw * 16640 + row * 130 + cl + j * 16 + l16] = f2bf(acc[i][j][r]);
          }
      }
      BARX();
      const int h = (h2 + ch) & 15;
      const size_t hb = ((size_t)(bi2 * 16 + h) * 2048 + s0 + rh * 128) * 128;
      const unsigned short* tl = smem8 + rh * 16640;
#pragma unroll
      for (int i = 0; i < 32; ++i) {
        int r = i * 4 + tg;
        float xa = bf2f(tl[r * 130 + d]);
        float xb2 = bf2f(tl[r * 130 + 64 + d]);
        float sn, cs;
        __sincosf((float)(s0 + rh * 128 + r) * fr, &sn, &cs);
        dst[hb + (size_t)r * 128 + d]      = f2bf((xa * cs - xb2 * sn) * scale);
        dst[hb + (size_t)r * 128 + 64 + d] = f2bf((xb2 * cs + xa * sn) * scale);
      }
    }
  } else {
    const int sc = tid & 15, dbase = (tid >> 4) & 15, rh = tid >> 8;
    for (int ch = 0; ch < 2; ++ch) {
      BARX();
      if (((w >> 1) & 1) == ch) {
        const int rw = w >> 2, cl = (w & 1) * 64;
#pragma unroll
        for (int i = 0; i < 8; ++i)
#pragma unroll
          for (int j = 0; j < 4; ++j) {
            int row = i * 16 + quad * 4;
            int col = cl + j * 16 + l16;
            ushort4 t4;
            t4.x = f2bf(acc[i][j][0]); t4.y = f2bf(acc[i][j][1]);
            t4.z = f2bf(acc[i][j][2]); t4.w = f2bf(acc[i][j][3]);
            *(ushort4*)&smem8[rw * 17408 + col * 136 + row] = t4;
          }
      }
      BARX();
      const int h = (h2 + ch) & 15;
      const size_t vrb = ((size_t)(bi2 * 16 + h) * 128) * 2048 + s0 + rh * 128;
#pragma unroll
      for (int vv = 0; vv < 8; ++vv) {
        int dd = dbase + vv * 16;
        uint4 val = *(const uint4*)&smem8[rh * 17408 + dd * 136 + sc * 8];
        *(uint4*)(ov + vrb + (size_t)dd * 2048 + sc * 8) = val;
      }
    }
  }
}

// ---------------- GEMM: C[M,N] = A[M,K](bf16) @ BT[N,K](bf16)^T ----------------
// 128x128 tile, BK=64, XOR-swizzled conflict-free LDS (R4 structure).
// Used only for the out projection (512-block grid).
template <int EPI>
__global__ __launch_bounds__(256) void gemm_bt_k(const unsigned short* __restrict__ A,
                                                 const unsigned short* __restrict__ BT,
                                                 int K, int N,
                                                 float* __restrict__ outF,
                                                 unsigned short* __restrict__ oq,
                                                 unsigned short* __restrict__ ok,
                                                 unsigned short* __restrict__ ov) {
  __shared__ __align__(16) unsigned short smem[17408];
  unsigned short* lA = smem;
  unsigned short* lB = smem + 8192;
  const int tid = threadIdx.x;
  const int w = tid >> 6, lane = tid & 63;
  const int quad = lane >> 4, l16 = lane & 15;
  const int m0 = blockIdx.y * 128, n0 = blockIdx.x * 128;
  const int wm = (w >> 1) * 64, wn = (w & 1) * 64;
  f32x4 acc[4][4] = {};
  const int srow = tid >> 3;
  const int schunk = (tid & 7) ^ (srow & 7);
  const unsigned short* gA = A + (size_t)(m0 + srow) * K + schunk * 8;
  const unsigned short* gB = BT + (size_t)(n0 + srow) * K + schunk * 8;
  char* ldA = (char*)lA + tid * 16;
  char* ldB = (char*)lB + tid * 16;
  const size_t rskip = (size_t)32 * K;
  for (int k0 = 0; k0 < K; k0 += 64) {
#pragma unroll
    for (int j = 0; j < 4; j++) {
      g2l16(gA + k0 + j * rskip, ldA + j * 4096);
      g2l16(gB + k0 + j * rskip, ldB + j * 4096);
    }
    __syncthreads();
#pragma unroll
    for (int ks = 0; ks < 2; ks++) {
      bf16x8 af[4], bfv[4];
#pragma unroll
      for (int i = 0; i < 4; i++)
        af[i] = *(const bf16x8*)((const char*)lA + (size_t)(wm + i * 16 + l16) * 128 +
                                 ((size_t)((ks * 4 + quad) ^ (l16 & 7)) * 16));
#pragma unroll
      for (int j = 0; j < 4; j++)
        bfv[j] = *(const bf16x8*)((const char*)lB + (size_t)(wn + j * 16 + l16) * 128 +
                                  ((size_t)((ks * 4 + quad) ^ (l16 & 7)) * 16));
#pragma unroll
      for (int i = 0; i < 4; i++)
#pragma unroll
        for (int j = 0; j < 4; j++)
          acc[i][j] = __builtin_amdgcn_mfma_f32_16x16x32_bf16(af[i], bfv[j], acc[i][j], 0, 0, 0);
    }
    __syncthreads();
  }
  if (EPI == 1) {
#pragma unroll
    for (int i = 0; i < 4; i++)
#pragma unroll
      for (int r = 0; r < 4; r++) {
        size_t rowb = (size_t)(m0 + wm + i * 16 + quad * 4 + r) * N;
#pragma unroll
        for (int j = 0; j < 4; j++)
          outF[rowb + n0 + wn + j * 16 + l16] = acc[i][j][r];
      }
  }
}

// ---------------- flash attention (R4 structure, g2l16-staged) ----------------
__global__ __launch_bounds__(256, 2) void attn_k(const unsigned short* __restrict__ qb,
                                                 const unsigned short* __restrict__ kb,
                                                 const unsigned short* __restrict__ vt,
                                                 unsigned short* __restrict__ ob) {
  __shared__ __align__(16) unsigned short lK[64 * 128];
  __shared__ __align__(16) unsigned short lV[128 * 64];
  __shared__ __align__(16) __bf16 pbuf[4][32 * 72];
  const int tid = threadIdx.x;
  const int w = tid >> 6, lane = tid & 63;
  const int quad = lane >> 4, l16 = lane & 15;
  const int qt = (blockIdx.y < 16) ? (int)blockIdx.x : 15 - (int)blockIdx.x;
  const int bh = blockIdx.y;
  const int bi = bh >> 4, h = bh & 15;
  const int q0w = qt * 128 + w * 32;
  const unsigned short* qp = qb + (size_t)bh * 2048 * 128;
  const unsigned short* kp = kb + (size_t)bh * 2048 * 128;
  const unsigned short* vp = vt + (size_t)bh * 128 * 2048;
  __bf16* pw = pbuf[w];

  bf16x8 qf[2][4];
#pragma unroll
  for (int rg = 0; rg < 2; rg++) {
    const unsigned short* qr = qp + (size_t)(q0w + rg * 16 + l16) * 128 + quad * 8;
#pragma unroll
    for (int st = 0; st < 4; st++) qf[rg][st] = *(const bf16x8*)(qr + st * 32);
  }
  f32x4 o[2][8] = {};
  f32x4 lsum[2] = {};

  const int krow = tid >> 4;
  const int kcg = (tid & 15) ^ krow;
  const int vd = tid >> 3;
  const int vsg = (tid & 7) ^ ((tid >> 3) & 7);
  unsigned short* lKdst = lK + (size_t)tid * 8;
  unsigned short* lVdst = lV + (size_t)tid * 8;

  const int nkt = 2 * qt + 2;
  const int myNkt = (q0w + 31) / 64 + 1;
  for (int kt = 0; kt < nkt; kt++) {
    const int kt0 = kt * 64;
#pragma unroll
    for (int j = 0; j < 4; j++) {
      g2l16(kp + (size_t)(kt0 + j * 16 + krow) * 128 + kcg * 8, lKdst + j * 2048);
      g2l16(vp + (size_t)(j * 32 + vd) * 2048 + kt0 + vsg * 8, lVdst + j * 2048);
    }
    __syncthreads();
    if (kt < myNkt) {
      f32x4 sc[2][4] = {};
#pragma unroll
      for (int ct = 0; ct < 4; ct++) {
        const int nrow = ct * 16 + l16;
#pragma unroll
        for (int st = 0; st < 4; st++) {
          bf16x8 kf = *(const bf16x8*)(lK + ((size_t)nrow * 16 + ((st * 4 + quad) ^ l16)) * 8);
          sc[0][ct] = __builtin_amdgcn_mfma_f32_16x16x32_bf16(qf[0][st], kf, sc[0][ct], 0, 0, 0);
          sc[1][ct] = __builtin_amdgcn_mfma_f32_16x16x32_bf16(qf[1][st], kf, sc[1][ct], 0, 0, 0);
        }
      }
      const bool needmask = (kt == myNkt - 1);
#pragma unroll
      for (int rg = 0; rg < 2; rg++)
#pragma unroll
        for (int ct = 0; ct < 4; ct++) {
          const int col = kt0 + ct * 16 + l16;
          const int rowb = q0w + rg * 16 + quad * 4;
#pragma unroll
          for (int r = 0; r < 4; r++) {
            float s = sc[rg][ct][r];
            if (needmask && col > rowb + r) s = -1e30f;
            float e = __expf(s);
            lsum[rg][r] += e;
            pw[(rg * 16 + quad * 4 + r) * 72 + ct * 16 + l16] = (__bf16)e;
          }
        }
      bf16x8 pf[2][2];
#pragma unroll
      for (int rg = 0; rg < 2; rg++)
#pragma unroll
        for (int sb = 0; sb < 2; sb++)
          pf[rg][sb] = *(const bf16x8*)(pw + (rg * 16 + l16) * 72 + sb * 32 + quad * 8);
#pragma unroll
      for (int dt = 0; dt < 8; dt++) {
#pragma unroll
        for (int sb = 0; sb < 2; sb++) {
          bf16x8 vf = *(const bf16x8*)(lV +
              ((size_t)(dt * 16 + l16) * 8 + ((sb * 4 + quad) ^ (l16 & 7))) * 8);
          o[0][dt] = __builtin_amdgcn_mfma_f32_16x16x32_bf16(pf[0][sb], vf, o[0][dt], 0, 0, 0);
          o[1][dt] = __builtin_amdgcn_mfma_f32_16x16x32_bf16(pf[1][sb], vf, o[1][dt], 0, 0, 0);
        }
      }
    }
    __syncthreads();
  }
#pragma unroll
  for (int m = 1; m < 16; m <<= 1)
#pragma unroll
    for (int rg = 0; rg < 2; rg++)
#pragma unroll
      for (int r = 0; r < 4; r++)
        lsum[rg][r] += __shfl_xor(lsum[rg][r], m, 64);
  float inv[2][4];
#pragma unroll
  for (int rg = 0; rg < 2; rg++)
#pragma unroll
    for (int r = 0; r < 4; r++) inv[rg][r] = 1.0f / lsum[rg][r];
#pragma unroll
  for (int rg = 0; rg < 2; rg++)
#pragma unroll
    for (int dt = 0; dt < 8; dt++)
#pragma unroll
      for (int r = 0; r < 4; r++)
        ob[(size_t)(bi * 2048 + q0w + rg * 16 + quad * 4 + r) * 2048 + h * 128 + dt * 16 + l16] =
            f2bf(o[rg][dt][r] * inv[rg][r]);
}

extern "C" void kernel_launch(void* const* d_in, const int* in_sizes, int n_in,
                              void* d_out, int out_size, void* d_ws, size_t ws_size,
                              hipStream_t stream) {
  const float* x = (const float*)d_in[0];
  const float* wqkv = (const float*)d_in[1];
  const float* wout = (const float*)d_in[2];
  // d_in[3] = mask, unused (causal analytically)
  char* ws = (char*)d_ws;
  const size_t MiB = 1ull << 20;
  unsigned short* xb    = (unsigned short*)(ws + 0);         // [4096,2048] bf16   16 MiB
  unsigned short* wqkvT = (unsigned short*)(ws + 16 * MiB);  // [6144,2048] bf16   24 MiB
  unsigned short* woutT = (unsigned short*)(ws + 40 * MiB);  // [2048,2048] bf16    8 MiB
  unsigned short* qb    = (unsigned short*)(ws + 48 * MiB);  // [32,2048,128] bf16 16 MiB
  unsigned short* kb    = (unsigned short*)(ws + 64 * MiB);  // [32,2048,128]      16 MiB
  unsigned short* vtb   = (unsigned short*)(ws + 80 * MiB);  // [32,128,2048]      16 MiB
  unsigned short* attnb = (unsigned short*)(ws + 96 * MiB);  // [4096,2048] bf16   16 MiB
  float* outF = (float*)d_out;

  prep_k<<<12288, 256, 0, stream>>>(x, wqkv, wout, xb, wqkvT, woutT);
  gemm8_qkv<<<384, 512, 0, stream>>>(xb, wqkvT, qb, kb, vtb);
  attn_k<<<dim3(16, 32), 256, 0, stream>>>(qb, kb, vtb, attnb);
  gemm_bt_k<1><<<dim3(16, 32), 256, 0, stream>>>(attnb, woutT, 2048, 2048, outF,
                                                 nullptr, nullptr, nullptr);
}

// Round 4
// 394.200 us; speedup vs baseline: 1.0944x; 1.0874x over previous
//
#include <hip/hip_runtime.h>

typedef __attribute__((ext_vector_type(8))) __bf16 bf16x8;
typedef __attribute__((ext_vector_type(4))) float f32x4;

__device__ __forceinline__ unsigned short f2bf(float x) {
  union { float f; unsigned int u; } v; v.f = x;
  unsigned int r = v.u + 0x7fffu + ((v.u >> 16) & 1u);
  return (unsigned short)(r >> 16);
}
__device__ __forceinline__ float bf2f(unsigned short x) {
  union { unsigned int u; float f; } v; v.u = ((unsigned int)x) << 16;
  return v.f;
}
__device__ __forceinline__ void g2l16(const void* g, void* l) {
  __builtin_amdgcn_global_load_lds((const __attribute__((address_space(1))) void*)g,
                                   (__attribute__((address_space(3))) void*)l, 16, 0, 0);
}

#define BARX()                                  \
  do {                                          \
    asm volatile("" ::: "memory");              \
    __builtin_amdgcn_s_barrier();               \
    asm volatile("" ::: "memory");              \
  } while (0)

// ---------------- fused input prep ----------------
__global__ __launch_bounds__(256) void prep_k(const float* __restrict__ x,
                                              const float* __restrict__ wq,
                                              const float* __restrict__ wo,
                                              unsigned short* __restrict__ xb,
                                              unsigned short* __restrict__ wqT,
                                              unsigned short* __restrict__ woT) {
  __shared__ unsigned short t[64][65];
  const int b = blockIdx.x;
  if (b < 8192) {
    int i = b * 256 + threadIdx.x;
    float4 v = ((const float4*)x)[i];
    ushort4 o;
    o.x = f2bf(v.x); o.y = f2bf(v.y); o.z = f2bf(v.z); o.w = f2bf(v.w);
    ((ushort4*)xb)[i] = o;
    return;
  }
  const float* in; unsigned short* out; int C, c0, r0;
  const int R = 2048;
  if (b < 11264) { int bb = b - 8192;  in = wq; out = wqT; C = 6144; c0 = (bb % 96) * 64; r0 = (bb / 96) * 64; }
  else           { int bb = b - 11264; in = wo; out = woT; C = 2048; c0 = (bb & 31) * 64; r0 = (bb >> 5) * 64; }
  const int tx = threadIdx.x & 63, tg = threadIdx.x >> 6;
#pragma unroll
  for (int i = 0; i < 16; i++) {
    int r = i * 4 + tg;
    t[r][tx] = f2bf(in[(size_t)(r0 + r) * C + c0 + tx]);
  }
  __syncthreads();
#pragma unroll
  for (int i = 0; i < 16; i++) {
    int c = i * 4 + tg;
    out[(size_t)(c0 + c) * R + r0 + tx] = t[tx][c];
  }
}

// ---------------- QKV GEMM: 256x256 8-phase (m201 template, plain HIP) ----------------
// R3 (resubmit): fused epilogue AMPUTATED (R1/R2 evidence: two-pass RoPE epilogue
// kept all 128 acc regs live across a sincos-heavy pass -> ~50 dwords/thread scratch
// spill -> WRITE_SIZE 92MB vs 49MB real, FETCH +98MB, ~80us scratch round-trip).
// Now: register-light direct store of raw q/k/v bf16; RoPE + V-transpose in rt_k.
// Also fixes R2's WAR race: STAGE(4t+8) (overwrites B0 slot, last read in P1)
// issues in P2, after P1's end barrier.
// Phases per K-tile t:
//   P0: read a0(8)+b0(4), STAGE(4t+7)=A1(next buf), bar, lgkm0, 16 MFMA r0-3 x c0-1, bar
//   P1: read b1(4),                                 bar, lgkm0, 16 MFMA r0-3 x c2-3, bar
//   P2: read a1(8), STAGE(4t+8)=B0, STAGE(4t+9)=B1, bar, lgkm0, 16 MFMA r4-7 x c0-1, bar
//   P3: STAGE(4t+10)=A0,                            bar,        16 MFMA r4-7 x c2-3,
//       vmcnt(6) [=3 half-tiles in flight], bar
__global__ __launch_bounds__(512, 2) void gemm8_qkv(const unsigned short* __restrict__ A,
                                                    const unsigned short* __restrict__ BT,
                                                    unsigned short* __restrict__ oq,
                                                    unsigned short* __restrict__ ok,
                                                    unsigned short* __restrict__ ovr) {
  __shared__ __align__(16) unsigned short smem8[65536];   // 131072 B
  const int tid = threadIdx.x;
  const int w = tid >> 6, lane = tid & 63;
  const int quad = lane >> 4, l16 = lane & 15;
  // bijective XCD swizzle (384 blocks, 384 % 8 == 0)
  const int id = (int)blockIdx.x;
  const int wg = (id & 7) * 48 + (id >> 3);
  const int bx = wg % 24, by = wg / 24;
  const int m0 = by * 256, n0 = bx * 256;
  const int wm = (w >> 2) * 128, wn = (w & 3) * 64;
  f32x4 acc[8][4] = {};

  // staging: per half-tile (128 rows x 64 k) each thread does 2 x g2l16(16B)
  const int rr = tid >> 3, csw = (tid & 7) ^ (rr & 7);
  const unsigned short* gA = A + (size_t)(m0 + rr) * 2048 + csw * 8;
  const unsigned short* gB = BT + (size_t)(n0 + rr) * 2048 + csw * 8;
  char* ldst = (char*)smem8 + tid * 16;
  auto STAGE = [&](int s) {
    if (s <= 127) {
      const int tau = s >> 2, u = s & 3, hh = u & 1;
      char* l = ldst + ((u < 2) ? 65536 : 0) + (tau & 1) * 32768 + hh * 16384;
      const unsigned short* g = ((u < 2) ? gB : gA) + (size_t)hh * 128 * 2048 + tau * 64;
      g2l16(g, (void*)l);
      g2l16(g + (size_t)64 * 2048, (void*)(l + 8192));
    }
  };

  // LDS read bases (XOR swizzle matches staging: phys chunk = logical ^ (row&7))
  const char* sA = (const char*)smem8 + (wm >> 7) * 16384 + l16 * 128;
  const char* sB = (const char*)smem8 + 65536 + (wn >> 7) * 16384 + ((wn & 64) + l16) * 128;
  const int x0 = (quad ^ (l16 & 7)) * 16;
  const int x1 = ((4 + quad) ^ (l16 & 7)) * 16;

#define KTILE(T, PB, NV)                                                                          \
  {                                                                                               \
    bf16x8 a0[4][2], a1[4][2], b0[2][2], b1[2][2];                                                \
    _Pragma("unroll") for (int i = 0; i < 4; ++i) {                                               \
      a0[i][0] = *(const bf16x8*)(sA + (PB) + i * 2048 + x0);                                     \
      a0[i][1] = *(const bf16x8*)(sA + (PB) + i * 2048 + x1);                                     \
    }                                                                                             \
    _Pragma("unroll") for (int j = 0; j < 2; ++j) {                                               \
      b0[j][0] = *(const bf16x8*)(sB + (PB) + j * 2048 + x0);                                     \
      b0[j][1] = *(const bf16x8*)(sB + (PB) + j * 2048 + x1);                                     \
    }                                                                                             \
    STAGE(4 * (T) + 7);                                                                           \
    BARX();                                                                                       \
    asm volatile("s_waitcnt lgkmcnt(0)" ::: "memory");                                            \
    __builtin_amdgcn_s_setprio(1);                                                                \
    _Pragma("unroll") for (int ks = 0; ks < 2; ++ks)                                              \
      _Pragma("unroll") for (int i = 0; i < 4; ++i)                                               \
        _Pragma("unroll") for (int j = 0; j < 2; ++j)                                             \
          acc[i][j] = __builtin_amdgcn_mfma_f32_16x16x32_bf16(a0[i][ks], b0[j][ks], acc[i][j], 0, 0, 0); \
    __builtin_amdgcn_s_setprio(0);                                                                \
    BARX();                                                                                       \
    _Pragma("unroll") for (int j = 0; j < 2; ++j) {                                               \
      b1[j][0] = *(const bf16x8*)(sB + (PB) + (j + 2) * 2048 + x0);                               \
      b1[j][1] = *(const bf16x8*)(sB + (PB) + (j + 2) * 2048 + x1);                               \
    }                                                                                             \
    BARX();                                                                                       \
    asm volatile("s_waitcnt lgkmcnt(0)" ::: "memory");                                            \
    __builtin_amdgcn_s_setprio(1);                                                                \
    _Pragma("unroll") for (int ks = 0; ks < 2; ++ks)                                              \
      _Pragma("unroll") for (int i = 0; i < 4; ++i)                                               \
        _Pragma("unroll") for (int j = 0; j < 2; ++j)                                             \
          acc[i][j + 2] = __builtin_amdgcn_mfma_f32_16x16x32_bf16(a0[i][ks], b1[j][ks], acc[i][j + 2], 0, 0, 0); \
    __builtin_amdgcn_s_setprio(0);                                                                \
    BARX();                                                                                       \
    _Pragma("unroll") for (int i = 0; i < 4; ++i) {                                               \
      a1[i][0] = *(const bf16x8*)(sA + (PB) + (i + 4) * 2048 + x0);                               \
      a1[i][1] = *(const bf16x8*)(sA + (PB) + (i + 4) * 2048 + x1);                               \
    }                                                                                             \
    STAGE(4 * (T) + 8);                                                                           \
    STAGE(4 * (T) + 9);                                                                           \
    BARX();                                                                                       \
    asm volatile("s_waitcnt lgkmcnt(0)" ::: "memory");                                            \
    __builtin_amdgcn_s_setprio(1);                                                                \
    _Pragma("unroll") for (int ks = 0; ks < 2; ++ks)                                              \
      _Pragma("unroll") for (int i = 0; i < 4; ++i)                                               \
        _Pragma("unroll") for (int j = 0; j < 2; ++j)                                             \
          acc[i + 4][j] = __builtin_amdgcn_mfma_f32_16x16x32_bf16(a1[i][ks], b0[j][ks], acc[i + 4][j], 0, 0, 0); \
    __builtin_amdgcn_s_setprio(0);                                                                \
    BARX();                                                                                       \
    STAGE(4 * (T) + 10);                                                                          \
    BARX();                                                                                       \
    __builtin_amdgcn_s_setprio(1);                                                                \
    _Pragma("unroll") for (int ks = 0; ks < 2; ++ks)                                              \
      _Pragma("unroll") for (int i = 0; i < 4; ++i)                                               \
        _Pragma("unroll") for (int j = 0; j < 2; ++j)                                             \
          acc[i + 4][j + 2] = __builtin_amdgcn_mfma_f32_16x16x32_bf16(a1[i][ks], b1[j][ks], acc[i + 4][j + 2], 0, 0, 0); \
    __builtin_amdgcn_s_setprio(0);                                                                \
    if ((NV) == 6) asm volatile("s_waitcnt vmcnt(6)" ::: "memory");                               \
    else if ((NV) == 0) asm volatile("s_waitcnt vmcnt(0)" ::: "memory");                          \
    BARX();                                                                                       \
  }

  // prologue: issue half-tiles 0..6 (tile0 {B0,B1,A0,A1} + tile1 {B0,B1,A0})
  for (int s = 0; s < 7; ++s) STAGE(s);
  asm volatile("s_waitcnt vmcnt(6)" ::: "memory");
  BARX();

  for (int t2 = 0; t2 < 32; t2 += 2) {
    KTILE(t2, 0, (t2 == 30) ? 0 : 6);
    KTILE(t2 + 1, 32768, (t2 + 1 == 31) ? -1 : 6);
  }
#undef KTILE

  // ---------------- trivial epilogue: raw bf16 store (register-light) ----------------
  // dst layout: [bi*16 + h][s][d]  (q -> oq, k -> ok, v -> ovr=attnb scratch)
  const int which = n0 >> 11;          // 0=q 1=k 2=v (256-tile never crosses)
  unsigned short* dst = (which == 0) ? oq : (which == 1 ? ok : ovr);
  const int bi2 = m0 >> 11, s0 = m0 & 2047;
  const int n0h = (n0 >> 7) & 15;      // head of tile's first 128-col half
#pragma unroll
  for (int i = 0; i < 8; ++i)
#pragma unroll
    for (int r = 0; r < 4; ++r) {
      const int s = s0 + wm + i * 16 + quad * 4 + r;
      const size_t rowb = ((size_t)(bi2 * 16) * 2048 + s) * 128;
#pragma unroll
      for (int j = 0; j < 4; ++j) {
        const int c = wn + j * 16 + l16;
        dst[rowb + (size_t)(n0h + (c >> 7)) * 262144 + (c & 127)] = f2bf(acc[i][j][r]);
      }
    }
}

// ---------------- RoPE (in-place on qb/kb) + V transpose (attnb -> vtb) ----------------
// blocks [0,1024):  which = b>>9 (0=q,1=k); bh = (b>>4)&31; sc = b&15 -> 128-row chunk.
//   in-place RoPE on [bh][sc*128..+127][0..127]; q additionally scaled by D^-1/2.
// blocks [1024,1536): V transpose: v_raw[bh][s][d] -> vt[bh][d][s], 64x65 LDS tiles.
__global__ __launch_bounds__(256) void rt_k(unsigned short* __restrict__ qb,
                                            unsigned short* __restrict__ kb,
                                            const unsigned short* __restrict__ vr,
                                            unsigned short* __restrict__ vt) {
  const int b = blockIdx.x;
  const int tid = threadIdx.x;
  if (b < 1024) {
    const int which = b >> 9, bh = (b >> 4) & 31, sc = b & 15;
    unsigned short* p = (which ? kb : qb) + (size_t)bh * 262144 + sc * 16384;
    const float scale = which ? 1.0f : 0.08838834764831845f;
    const int d = tid & 63, tg = tid >> 6;
    const float fr = exp2f(-(float)d * (13.287712379549449f / 64.0f));
#pragma unroll
    for (int i = 0; i < 32; ++i) {
      const int r = i * 4 + tg;
      float a = bf2f(p[r * 128 + d]);
      float bb = bf2f(p[r * 128 + 64 + d]);
      float sn, cs;
      __sincosf((float)(sc * 128 + r) * fr, &sn, &cs);
      p[r * 128 + d]      = f2bf((a * cs - bb * sn) * scale);
      p[r * 128 + 64 + d] = f2bf((bb * cs + a * sn) * scale);
    }
    return;
  }
  __shared__ unsigned short t[64][65];
  const int bb = b - 1024, bh = bb >> 4, sc = bb & 15;
  const unsigned short* src = vr + (size_t)bh * 262144 + sc * 16384;
  unsigned short* dst = vt + (size_t)bh * 262144 + sc * 128;
  const int tx = tid & 63, tg = tid >> 6;
#pragma unroll
  for (int q4 = 0; q4 < 4; ++q4) {
    const int sy = q4 >> 1, dx = q4 & 1;
#pragma unroll
    for (int i = 0; i < 16; ++i) {
      const int r = i * 4 + tg;
      t[r][tx] = src[(size_t)(sy * 64 + r) * 128 + dx * 64 + tx];
    }
    __syncthreads();
#pragma unroll
    for (int i = 0; i < 16; ++i) {
      const int c = i * 4 + tg;
      dst[(size_t)(dx * 64 + c) * 2048 + sy * 64 + tx] = t[tx][c];
    }
    __syncthreads();
  }
}

// ---------------- GEMM: C[M,N] = A[M,K](bf16) @ BT[N,K](bf16)^T ----------------
// 128x128 tile, BK=64, XOR-swizzled conflict-free LDS. Out projection only.
template <int EPI>
__global__ __launch_bounds__(256) void gemm_bt_k(const unsigned short* __restrict__ A,
                                                 const unsigned short* __restrict__ BT,
                                                 int K, int N,
                                                 float* __restrict__ outF) {
  __shared__ __align__(16) unsigned short smem[17408];
  unsigned short* lA = smem;
  unsigned short* lB = smem + 8192;
  const int tid = threadIdx.x;
  const int w = tid >> 6, lane = tid & 63;
  const int quad = lane >> 4, l16 = lane & 15;
  const int m0 = blockIdx.y * 128, n0 = blockIdx.x * 128;
  const int wm = (w >> 1) * 64, wn = (w & 1) * 64;
  f32x4 acc[4][4] = {};
  const int srow = tid >> 3;
  const int schunk = (tid & 7) ^ (srow & 7);
  const unsigned short* gA = A + (size_t)(m0 + srow) * K + schunk * 8;
  const unsigned short* gB = BT + (size_t)(n0 + srow) * K + schunk * 8;
  char* ldA = (char*)lA + tid * 16;
  char* ldB = (char*)lB + tid * 16;
  const size_t rskip = (size_t)32 * K;
  for (int k0 = 0; k0 < K; k0 += 64) {
#pragma unroll
    for (int j = 0; j < 4; j++) {
      g2l16(gA + k0 + j * rskip, ldA + j * 4096);
      g2l16(gB + k0 + j * rskip, ldB + j * 4096);
    }
    __syncthreads();
#pragma unroll
    for (int ks = 0; ks < 2; ks++) {
      bf16x8 af[4], bfv[4];
#pragma unroll
      for (int i = 0; i < 4; i++)
        af[i] = *(const bf16x8*)((const char*)lA + (size_t)(wm + i * 16 + l16) * 128 +
                                 ((size_t)((ks * 4 + quad) ^ (l16 & 7)) * 16));
#pragma unroll
      for (int j = 0; j < 4; j++)
        bfv[j] = *(const bf16x8*)((const char*)lB + (size_t)(wn + j * 16 + l16) * 128 +
                                  ((size_t)((ks * 4 + quad) ^ (l16 & 7)) * 16));
#pragma unroll
      for (int i = 0; i < 4; i++)
#pragma unroll
        for (int j = 0; j < 4; j++)
          acc[i][j] = __builtin_amdgcn_mfma_f32_16x16x32_bf16(af[i], bfv[j], acc[i][j], 0, 0, 0);
    }
    __syncthreads();
  }
#pragma unroll
  for (int i = 0; i < 4; i++)
#pragma unroll
    for (int r = 0; r < 4; r++) {
      size_t rowb = (size_t)(m0 + wm + i * 16 + quad * 4 + r) * N;
#pragma unroll
      for (int j = 0; j < 4; j++)
        outF[rowb + n0 + wn + j * 16 + l16] = acc[i][j][r];
    }
}

// ---------------- flash attention (R4 structure, g2l16-staged) ----------------
__global__ __launch_bounds__(256, 2) void attn_k(const unsigned short* __restrict__ qb,
                                                 const unsigned short* __restrict__ kb,
                                                 const unsigned short* __restrict__ vt,
                                                 unsigned short* __restrict__ ob) {
  __shared__ __align__(16) unsigned short lK[64 * 128];
  __shared__ __align__(16) unsigned short lV[128 * 64];
  __shared__ __align__(16) __bf16 pbuf[4][32 * 72];
  const int tid = threadIdx.x;
  const int w = tid >> 6, lane = tid & 63;
  const int quad = lane >> 4, l16 = lane & 15;
  const int qt = (blockIdx.y < 16) ? (int)blockIdx.x : 15 - (int)blockIdx.x;
  const int bh = blockIdx.y;
  const int bi = bh >> 4, h = bh & 15;
  const int q0w = qt * 128 + w * 32;
  const unsigned short* qp = qb + (size_t)bh * 2048 * 128;
  const unsigned short* kp = kb + (size_t)bh * 2048 * 128;
  const unsigned short* vp = vt + (size_t)bh * 128 * 2048;
  __bf16* pw = pbuf[w];

  bf16x8 qf[2][4];
#pragma unroll
  for (int rg = 0; rg < 2; rg++) {
    const unsigned short* qr = qp + (size_t)(q0w + rg * 16 + l16) * 128 + quad * 8;
#pragma unroll
    for (int st = 0; st < 4; st++) qf[rg][st] = *(const bf16x8*)(qr + st * 32);
  }
  f32x4 o[2][8] = {};
  f32x4 lsum[2] = {};

  const int krow = tid >> 4;
  const int kcg = (tid & 15) ^ krow;
  const int vd = tid >> 3;
  const int vsg = (tid & 7) ^ ((tid >> 3) & 7);
  unsigned short* lKdst = lK + (size_t)tid * 8;
  unsigned short* lVdst = lV + (size_t)tid * 8;

  const int nkt = 2 * qt + 2;
  const int myNkt = (q0w + 31) / 64 + 1;
  for (int kt = 0; kt < nkt; kt++) {
    const int kt0 = kt * 64;
#pragma unroll
    for (int j = 0; j < 4; j++) {
      g2l16(kp + (size_t)(kt0 + j * 16 + krow) * 128 + kcg * 8, lKdst + j * 2048);
      g2l16(vp + (size_t)(j * 32 + vd) * 2048 + kt0 + vsg * 8, lVdst + j * 2048);
    }
    __syncthreads();
    if (kt < myNkt) {
      f32x4 sc[2][4] = {};
#pragma unroll
      for (int ct = 0; ct < 4; ct++) {
        const int nrow = ct * 16 + l16;
#pragma unroll
        for (int st = 0; st < 4; st++) {
          bf16x8 kf = *(const bf16x8*)(lK + ((size_t)nrow * 16 + ((st * 4 + quad) ^ l16)) * 8);
          sc[0][ct] = __builtin_amdgcn_mfma_f32_16x16x32_bf16(qf[0][st], kf, sc[0][ct], 0, 0, 0);
          sc[1][ct] = __builtin_amdgcn_mfma_f32_16x16x32_bf16(qf[1][st], kf, sc[1][ct], 0, 0, 0);
        }
      }
      const bool needmask = (kt == myNkt - 1);
#pragma unroll
      for (int rg = 0; rg < 2; rg++)
#pragma unroll
        for (int ct = 0; ct < 4; ct++) {
          const int col = kt0 + ct * 16 + l16;
          const int rowb = q0w + rg * 16 + quad * 4;
#pragma unroll
          for (int r = 0; r < 4; r++) {
            float s = sc[rg][ct][r];
            if (needmask && col > rowb + r) s = -1e30f;
            float e = __expf(s);
            lsum[rg][r] += e;
            pw[(rg * 16 + quad * 4 + r) * 72 + ct * 16 + l16] = (__bf16)e;
          }
        }
      bf16x8 pf[2][2];
#pragma unroll
      for (int rg = 0; rg < 2; rg++)
#pragma unroll
        for (int sb = 0; sb < 2; sb++)
          pf[rg][sb] = *(const bf16x8*)(pw + (rg * 16 + l16) * 72 + sb * 32 + quad * 8);
#pragma unroll
      for (int dt = 0; dt < 8; dt++) {
#pragma unroll
        for (int sb = 0; sb < 2; sb++) {
          bf16x8 vf = *(const bf16x8*)(lV +
              ((size_t)(dt * 16 + l16) * 8 + ((sb * 4 + quad) ^ (l16 & 7))) * 8);
          o[0][dt] = __builtin_amdgcn_mfma_f32_16x16x32_bf16(pf[0][sb], vf, o[0][dt], 0, 0, 0);
          o[1][dt] = __builtin_amdgcn_mfma_f32_16x16x32_bf16(pf[1][sb], vf, o[1][dt], 0, 0, 0);
        }
      }
    }
    __syncthreads();
  }
#pragma unroll
  for (int m = 1; m < 16; m <<= 1)
#pragma unroll
    for (int rg = 0; rg < 2; rg++)
#pragma unroll
      for (int r = 0; r < 4; r++)
        lsum[rg][r] += __shfl_xor(lsum[rg][r], m, 64);
  float inv[2][4];
#pragma unroll
  for (int rg = 0; rg < 2; rg++)
#pragma unroll
    for (int r = 0; r < 4; r++) inv[rg][r] = 1.0f / lsum[rg][r];
#pragma unroll
  for (int rg = 0; rg < 2; rg++)
#pragma unroll
    for (int dt = 0; dt < 8; dt++)
#pragma unroll
      for (int r = 0; r < 4; r++)
        ob[(size_t)(bi * 2048 + q0w + rg * 16 + quad * 4 + r) * 2048 + h * 128 + dt * 16 + l16] =
            f2bf(o[rg][dt][r] * inv[rg][r]);
}

extern "C" void kernel_launch(void* const* d_in, const int* in_sizes, int n_in,
                              void* d_out, int out_size, void* d_ws, size_t ws_size,
                              hipStream_t stream) {
  const float* x = (const float*)d_in[0];
  const float* wqkv = (const float*)d_in[1];
  const float* wout = (const float*)d_in[2];
  // d_in[3] = mask, unused (causal analytically)
  char* ws = (char*)d_ws;
  const size_t MiB = 1ull << 20;
  unsigned short* xb    = (unsigned short*)(ws + 0);         // [4096,2048] bf16   16 MiB
  unsigned short* wqkvT = (unsigned short*)(ws + 16 * MiB);  // [6144,2048] bf16   24 MiB
  unsigned short* woutT = (unsigned short*)(ws + 40 * MiB);  // [2048,2048] bf16    8 MiB
  unsigned short* qb    = (unsigned short*)(ws + 48 * MiB);  // [32,2048,128] bf16 16 MiB
  unsigned short* kb    = (unsigned short*)(ws + 64 * MiB);  // [32,2048,128]      16 MiB
  unsigned short* vtb   = (unsigned short*)(ws + 80 * MiB);  // [32,128,2048]      16 MiB
  unsigned short* attnb = (unsigned short*)(ws + 96 * MiB);  // v_raw, then attn out
  float* outF = (float*)d_out;

  prep_k<<<12288, 256, 0, stream>>>(x, wqkv, wout, xb, wqkvT, woutT);
  gemm8_qkv<<<384, 512, 0, stream>>>(xb, wqkvT, qb, kb, attnb);
  rt_k<<<1536, 256, 0, stream>>>(qb, kb, attnb, vtb);
  attn_k<<<dim3(16, 32), 256, 0, stream>>>(qb, kb, vtb, attnb);
  gemm_bt_k<1><<<dim3(16, 32), 256, 0, stream>>>(attnb, woutT, 2048, 2048, outF);
}